// Round 1
// baseline (3903.114 us; speedup 1.0000x reference)
//
#include <hip/hip_runtime.h>
#include <math.h>

#define NN      50000      // N_NODES
#define BP      4096       // N_PAIRS_MAP
#define NE      500000     // N_EDGES
#define NP      1000000    // N_SCORE_PAIRS
#define FEAT    300
#define HID     128
#define HEADS   3
#define OUTC    10
#define HC1     (HEADS*HID)   // 384
#define NEG_SLOPE 0.2f

static inline int cdiv(int a, int b) { return (a + b - 1) / b; }

// ---------- helpers ----------
__device__ inline unsigned enc_f(float f) {
    unsigned b = __float_as_uint(f);
    return (b & 0x80000000u) ? ~b : (b | 0x80000000u);
}
__device__ inline float dec_f(unsigned u) {
    return (u & 0x80000000u) ? __uint_as_float(u ^ 0x80000000u) : __uint_as_float(~u);
}
__device__ inline float leaky(float x) { return x > 0.f ? x : NEG_SLOPE * x; }

// ---------- fill ----------
__global__ void fill_f32(float* p, float v, long n) {
    long i = (long)blockIdx.x * blockDim.x + threadIdx.x;
    if (i < n) p[i] = v;
}
__global__ void fill_u32(unsigned* p, unsigned v, long n) {
    long i = (long)blockIdx.x * blockDim.x + threadIdx.x;
    if (i < n) p[i] = v;
}

// ---------- generic tiled fp32 GEMM ----------
// NT=false: C[M,N] = scale * A[M,K] @ B[K,N] (+bias[N]) (+addsrc[M,N])
// NT=true : B given as [N,K] row-major (i.e., C = A @ B^T)
template <bool NT>
__global__ void gemm_kernel(const float* __restrict__ A, const float* __restrict__ B,
                            const float* __restrict__ bias, const float* __restrict__ addsrc,
                            float* __restrict__ C, int M, int N, int K, float scale) {
    __shared__ float As[16][17];
    __shared__ float Bs[16][17];
    int tx = threadIdx.x, ty = threadIdx.y;
    int row = blockIdx.y * 16 + ty;
    int col = blockIdx.x * 16 + tx;
    float acc = 0.f;
    for (int k0 = 0; k0 < K; k0 += 16) {
        int ka = k0 + tx;
        As[ty][tx] = (row < M && ka < K) ? A[(long)row * K + ka] : 0.f;
        if (!NT) {
            int kb = k0 + ty;
            Bs[ty][tx] = (kb < K && col < N) ? B[(long)kb * N + col] : 0.f;
        } else {
            int kb = k0 + tx;
            int jr = blockIdx.x * 16 + ty;
            Bs[ty][tx] = (jr < N && kb < K) ? B[(long)jr * K + kb] : 0.f;
        }
        __syncthreads();
        if (!NT) {
#pragma unroll
            for (int kk = 0; kk < 16; kk++) acc += As[ty][kk] * Bs[kk][tx];
        } else {
#pragma unroll
            for (int kk = 0; kk < 16; kk++) acc += As[ty][kk] * Bs[tx][kk];
        }
        __syncthreads();
    }
    if (row < M && col < N) {
        float v = acc * scale;
        if (bias) v += bias[col];
        if (addsrc) v += addsrc[(long)row * N + col];
        C[(long)row * N + col] = v;
    }
}

// ---------- row softmax over [R, n] ----------
__global__ void softmax_rows(float* __restrict__ S, int n) {
    int row = blockIdx.x;
    float* p = S + (long)row * n;
    __shared__ float red[256];
    int tid = threadIdx.x;
    float m = -1e30f;
    for (int j = tid; j < n; j += 256) m = fmaxf(m, p[j]);
    red[tid] = m; __syncthreads();
    for (int s = 128; s > 0; s >>= 1) { if (tid < s) red[tid] = fmaxf(red[tid], red[tid + s]); __syncthreads(); }
    m = red[0]; __syncthreads();
    float sum = 0.f;
    for (int j = tid; j < n; j += 256) { float e = expf(p[j] - m); p[j] = e; sum += e; }
    red[tid] = sum; __syncthreads();
    for (int s = 128; s > 0; s >>= 1) { if (tid < s) red[tid] += red[tid + s]; __syncthreads(); }
    float inv = 1.0f / red[0];
    for (int j = tid; j < n; j += 256) p[j] *= inv;
}

// ---------- scatter (last write wins, numpy semantics) ----------
__global__ void scatter_init(int* last, const int* __restrict__ com, int B) {
    int i = blockIdx.x * blockDim.x + threadIdx.x;
    if (i < B) last[com[i]] = -1;
}
__global__ void scatter_max(int* last, const int* __restrict__ com, int B) {
    int i = blockIdx.x * blockDim.x + threadIdx.x;
    if (i < B) atomicMax(&last[com[i]], i);
}
__global__ void scatter_write(const int* __restrict__ last, const int* __restrict__ com,
                              const float* __restrict__ fused, float* __restrict__ x, int B, int D) {
    int i = blockIdx.x;
    int node = com[i];
    if (last[node] != i) return;
    for (int c = threadIdx.x; c < D; c += blockDim.x)
        x[(long)node * D + c] = fused[(long)i * D + c];
}

// ---------- GAT per-node attention coefficients ----------
__global__ void node_attn_coef(const float* __restrict__ h, const float* __restrict__ a_src,
                               const float* __restrict__ a_dst, float* __restrict__ es,
                               float* __restrict__ ed, int N, int H, int C) {
    int idx = blockIdx.x * blockDim.x + threadIdx.x;
    if (idx >= N * H) return;
    int n = idx / H, hh = idx % H;
    const float* hp = h + (long)n * H * C + (long)hh * C;
    const float* as = a_src + hh * C;
    const float* ad = a_dst + hh * C;
    float s = 0.f, d = 0.f;
    for (int c = 0; c < C; c++) { float v = hp[c]; s += v * as[c]; d += v * ad[c]; }
    es[idx] = s; ed[idx] = d;
}

// ---------- edge passes ----------
__global__ void edge_max_k(const int* __restrict__ src, const int* __restrict__ dst, int E, int N,
                           const float* __restrict__ es, const float* __restrict__ ed,
                           unsigned* __restrict__ m, int H) {
    int eid = blockIdx.x * blockDim.x + threadIdx.x;
    int ET = E + N;
    if (eid >= ET) return;
    int s = eid < E ? src[eid] : eid - E;
    int d = eid < E ? dst[eid] : eid - E;
    for (int h = 0; h < H; h++) {
        float e = leaky(es[s * H + h] + ed[d * H + h]);
        atomicMax(&m[d * H + h], enc_f(e));
    }
}
__global__ void edge_denom_k(const int* __restrict__ src, const int* __restrict__ dst, int E, int N,
                             const float* __restrict__ es, const float* __restrict__ ed,
                             const unsigned* __restrict__ m, float* __restrict__ denom, int H) {
    int eid = blockIdx.x * blockDim.x + threadIdx.x;
    int ET = E + N;
    if (eid >= ET) return;
    int s = eid < E ? src[eid] : eid - E;
    int d = eid < E ? dst[eid] : eid - E;
    for (int h = 0; h < H; h++) {
        float e = leaky(es[s * H + h] + ed[d * H + h]);
        atomicAdd(&denom[d * H + h], expf(e - dec_f(m[d * H + h])));
    }
}
// layer1 aggregate: one block (128 threads) per edge, H=3, C=128
__global__ void edge_agg1(const int* __restrict__ src, const int* __restrict__ dst, int E, int N,
                          const float* __restrict__ es, const float* __restrict__ ed,
                          const unsigned* __restrict__ m, const float* __restrict__ denom,
                          const float* __restrict__ h, float* __restrict__ out) {
    int eid = blockIdx.x;
    int ET = E + N;
    if (eid >= ET) return;
    int tid = threadIdx.x;
    int s = eid < E ? src[eid] : eid - E;
    int d = eid < E ? dst[eid] : eid - E;
    __shared__ float alpha[HEADS];
    if (tid < HEADS) {
        float e = leaky(es[s * HEADS + tid] + ed[d * HEADS + tid]);
        alpha[tid] = expf(e - dec_f(m[d * HEADS + tid])) / (denom[d * HEADS + tid] + 1e-16f);
    }
    __syncthreads();
    const float* hs = h + (long)s * HC1;
    float* od = out + (long)d * HC1;
    for (int j = tid; j < HC1; j += 128)
        atomicAdd(&od[j], hs[j] * alpha[j >> 7]);   // C=128 -> head = j/128
}
// layer2 aggregate: thread per edge, H=1, C=10
__global__ void edge_agg2(const int* __restrict__ src, const int* __restrict__ dst, int E, int N,
                          const float* __restrict__ es, const float* __restrict__ ed,
                          const unsigned* __restrict__ m, const float* __restrict__ denom,
                          const float* __restrict__ h, float* __restrict__ out) {
    int eid = blockIdx.x * blockDim.x + threadIdx.x;
    int ET = E + N;
    if (eid >= ET) return;
    int s = eid < E ? src[eid] : eid - E;
    int d = eid < E ? dst[eid] : eid - E;
    float e = leaky(es[s] + ed[d]);
    float alpha = expf(e - dec_f(m[d])) / (denom[d] + 1e-16f);
    const float* hs = h + (long)s * OUTC;
    float* od = out + (long)d * OUTC;
#pragma unroll
    for (int c = 0; c < OUTC; c++) atomicAdd(&od[c], hs[c] * alpha);
}

// ---------- bias (+ optional ELU), in place ----------
__global__ void bias_act(float* __restrict__ x, const float* __restrict__ bias, long total, int N, int do_elu) {
    long i = (long)blockIdx.x * blockDim.x + threadIdx.x;
    if (i >= total) return;
    int j = (int)(i % N);
    float v = x[i] + bias[j];
    if (do_elu) v = v > 0.f ? v : (expf(v) - 1.0f);
    x[i] = v;
}

// ---------- pair scores ----------
__global__ void pair_score(const int* __restrict__ pairs, const float* __restrict__ emb,
                           float* __restrict__ out, int P) {
    int p = blockIdx.x * blockDim.x + threadIdx.x;
    if (p >= P) return;
    int i0 = pairs[2 * p], i1 = pairs[2 * p + 1];
    const float* a = emb + (long)i0 * OUTC;
    const float* b = emb + (long)i1 * OUTC;
    float s = 0.f;
#pragma unroll
    for (int c = 0; c < OUTC; c++) s += a[c] * b[c];
    out[p] = s;
}

extern "C" void kernel_launch(void* const* d_in, const int* in_sizes, int n_in,
                              void* d_out, int out_size, void* d_ws, size_t ws_size,
                              hipStream_t stream) {
    const float* fsub = (const float*)d_in[0];
    const float* fcom = (const float*)d_in[1];
    float*       x    = (float*)d_in[2];          // scatter target (harness restores each launch)
    const int*   com  = (const int*)d_in[3];
    const int*   ei   = (const int*)d_in[4];
    const int*   pidx = (const int*)d_in[5];
    const float* Wq = (const float*)d_in[6];  const float* bq = (const float*)d_in[7];
    const float* Wk = (const float*)d_in[8];  const float* bk = (const float*)d_in[9];
    const float* Wv = (const float*)d_in[10]; const float* bv = (const float*)d_in[11];
    const float* Wf = (const float*)d_in[12]; const float* bf = (const float*)d_in[13];
    const float* W1 = (const float*)d_in[14];
    const float* as1 = (const float*)d_in[15]; const float* ad1 = (const float*)d_in[16];
    const float* b1 = (const float*)d_in[17];
    const float* W2 = (const float*)d_in[18];
    const float* as2 = (const float*)d_in[19]; const float* ad2 = (const float*)d_in[20];
    const float* b2 = (const float*)d_in[21];
    float* out = (float*)d_out;

    const int* src = ei;
    const int* dst = ei + NE;

    char* ws = (char*)d_ws;
    // ---- phase 1 layout (attention) ----
    float* S    = (float*)(ws + 0);          // 4096*4096*4       = 67,108,864
    float* q    = (float*)(ws + 67108864);   // 4096*300*4        =  4,915,200
    float* kbuf = (float*)(ws + 72024064);
    float* vbuf = (float*)(ws + 76939264);
    float* attn = (float*)(ws + 81854464);
    float* fus  = (float*)(ws + 86769664);   // ends 91,684,864
    // ---- phase 2 layout (GAT) — reuses offset 0 after scatter ----
    float*    h1   = (float*)(ws + 0);          // 50000*384*4 = 76,800,000
    float*    out1 = (float*)(ws + 76800000);   // 76,800,000  -> ends 153,600,000
    char*     sm   = ws + 153600000;
    float*    es1  = (float*)(sm);               sm += 600000;   // 50000*3*4
    float*    ed1  = (float*)(sm);               sm += 600000;
    unsigned* m1   = (unsigned*)(sm);            sm += 600000;
    float*    den1 = (float*)(sm);               sm += 600000;
    float*    h2   = (float*)(sm);               sm += 2000000;  // 50000*10*4
    float*    embp = (float*)(sm);               sm += 2000000;
    float*    es2  = (float*)(sm);               sm += 200000;
    float*    ed2  = (float*)(sm);               sm += 200000;
    unsigned* m2   = (unsigned*)(sm);            sm += 200000;
    float*    den2 = (float*)(sm);               sm += 200000;
    int*      last = (int*)(sm);                 sm += 200000;   // total ~158.9 MB

    dim3 tb(16, 16);
    const float inv_sqrt_d = 1.0f / sqrtf((float)FEAT);

    // ===== 1. cross attention =====
    hipLaunchKernelGGL((gemm_kernel<false>), dim3(cdiv(FEAT,16), cdiv(BP,16)), tb, 0, stream,
                       fsub, Wq, bq, nullptr, q, BP, FEAT, FEAT, 1.0f);
    hipLaunchKernelGGL((gemm_kernel<false>), dim3(cdiv(FEAT,16), cdiv(BP,16)), tb, 0, stream,
                       fcom, Wk, bk, nullptr, kbuf, BP, FEAT, FEAT, 1.0f);
    hipLaunchKernelGGL((gemm_kernel<false>), dim3(cdiv(FEAT,16), cdiv(BP,16)), tb, 0, stream,
                       fcom, Wv, bv, nullptr, vbuf, BP, FEAT, FEAT, 1.0f);
    // S = (q @ k^T) * inv_sqrt_d
    hipLaunchKernelGGL((gemm_kernel<true>), dim3(cdiv(BP,16), cdiv(BP,16)), tb, 0, stream,
                       q, kbuf, nullptr, nullptr, S, BP, BP, FEAT, inv_sqrt_d);
    hipLaunchKernelGGL(softmax_rows, dim3(BP), dim3(256), 0, stream, S, BP);
    // attn = fsub + S @ v
    hipLaunchKernelGGL((gemm_kernel<false>), dim3(cdiv(FEAT,16), cdiv(BP,16)), tb, 0, stream,
                       S, vbuf, nullptr, fsub, attn, BP, FEAT, BP, 1.0f);
    // fused = attn @ Wf + bf
    hipLaunchKernelGGL((gemm_kernel<false>), dim3(cdiv(FEAT,16), cdiv(BP,16)), tb, 0, stream,
                       attn, Wf, bf, nullptr, fus, BP, FEAT, FEAT, 1.0f);

    // ===== 2. scatter fused into x (last write wins) =====
    hipLaunchKernelGGL(scatter_init, dim3(cdiv(BP,256)), dim3(256), 0, stream, last, com, BP);
    hipLaunchKernelGGL(scatter_max,  dim3(cdiv(BP,256)), dim3(256), 0, stream, last, com, BP);
    hipLaunchKernelGGL(scatter_write, dim3(BP), dim3(128), 0, stream, last, com, fus, x, BP, FEAT);

    // ===== 3. GAT layer 1 =====
    hipLaunchKernelGGL((gemm_kernel<false>), dim3(cdiv(HC1,16), cdiv(NN,16)), tb, 0, stream,
                       x, W1, nullptr, nullptr, h1, NN, HC1, FEAT, 1.0f);
    hipLaunchKernelGGL(node_attn_coef, dim3(cdiv(NN*HEADS,256)), dim3(256), 0, stream,
                       h1, as1, ad1, es1, ed1, NN, HEADS, HID);
    hipLaunchKernelGGL(fill_u32, dim3(cdiv(NN*HEADS,256)), dim3(256), 0, stream, m1, 0u, (long)NN*HEADS);
    hipLaunchKernelGGL(fill_f32, dim3(cdiv(NN*HEADS,256)), dim3(256), 0, stream, den1, 0.f, (long)NN*HEADS);
    hipLaunchKernelGGL(fill_f32, dim3(cdiv(NN*HC1,256)), dim3(256), 0, stream, out1, 0.f, (long)NN*HC1);
    int ET = NE + NN;
    hipLaunchKernelGGL(edge_max_k,   dim3(cdiv(ET,256)), dim3(256), 0, stream, src, dst, NE, NN, es1, ed1, m1, HEADS);
    hipLaunchKernelGGL(edge_denom_k, dim3(cdiv(ET,256)), dim3(256), 0, stream, src, dst, NE, NN, es1, ed1, m1, den1, HEADS);
    hipLaunchKernelGGL(edge_agg1, dim3(ET), dim3(128), 0, stream, src, dst, NE, NN, es1, ed1, m1, den1, h1, out1);
    // out1 = elu(out1 + b1)
    hipLaunchKernelGGL(bias_act, dim3(cdiv(NN*HC1,256)), dim3(256), 0, stream, out1, b1, (long)NN*HC1, HC1, 1);

    // ===== 4. GAT layer 2 =====
    hipLaunchKernelGGL((gemm_kernel<false>), dim3(cdiv(OUTC,16), cdiv(NN,16)), tb, 0, stream,
                       out1, W2, nullptr, nullptr, h2, NN, OUTC, HC1, 1.0f);
    hipLaunchKernelGGL(node_attn_coef, dim3(cdiv(NN,256)), dim3(256), 0, stream,
                       h2, as2, ad2, es2, ed2, NN, 1, OUTC);
    hipLaunchKernelGGL(fill_u32, dim3(cdiv(NN,256)), dim3(256), 0, stream, m2, 0u, (long)NN);
    hipLaunchKernelGGL(fill_f32, dim3(cdiv(NN,256)), dim3(256), 0, stream, den2, 0.f, (long)NN);
    hipLaunchKernelGGL(fill_f32, dim3(cdiv(NN*OUTC,256)), dim3(256), 0, stream, embp, 0.f, (long)NN*OUTC);
    hipLaunchKernelGGL(edge_max_k,   dim3(cdiv(ET,256)), dim3(256), 0, stream, src, dst, NE, NN, es2, ed2, m2, 1);
    hipLaunchKernelGGL(edge_denom_k, dim3(cdiv(ET,256)), dim3(256), 0, stream, src, dst, NE, NN, es2, ed2, m2, den2, 1);
    hipLaunchKernelGGL(edge_agg2, dim3(cdiv(ET,256)), dim3(256), 0, stream, src, dst, NE, NN, es2, ed2, m2, den2, h2, embp);
    // emb = embp + b2
    hipLaunchKernelGGL(bias_act, dim3(cdiv(NN*OUTC,256)), dim3(256), 0, stream, embp, b2, (long)NN*OUTC, OUTC, 0);

    // ===== 5. pair scores =====
    hipLaunchKernelGGL(pair_score, dim3(cdiv(NP,256)), dim3(256), 0, stream, pidx, embp, out, NP);
}

// Round 2
// 2797.025 us; speedup vs baseline: 1.3955x; 1.3955x over previous
//
#include <hip/hip_runtime.h>
#include <math.h>

#define NN      50000      // N_NODES
#define BP      4096       // N_PAIRS_MAP
#define NE      500000     // N_EDGES
#define NP      1000000    // N_SCORE_PAIRS
#define FEAT    300
#define HID     128
#define HEADS   3
#define OUTC    10
#define HC1     (HEADS*HID)   // 384
#define NEG_SLOPE 0.2f

static inline int cdiv(int a, int b) { return (a + b - 1) / b; }

// ---------- helpers ----------
__device__ inline unsigned enc_f(float f) {
    unsigned b = __float_as_uint(f);
    return (b & 0x80000000u) ? ~b : (b | 0x80000000u);
}
__device__ inline float dec_f(unsigned u) {
    return (u & 0x80000000u) ? __uint_as_float(u ^ 0x80000000u) : __uint_as_float(~u);
}
__device__ inline float leaky(float x) { return x > 0.f ? x : NEG_SLOPE * x; }

// ---------- fill ----------
__global__ void fill_f32(float* p, float v, long n) {
    long i = (long)blockIdx.x * blockDim.x + threadIdx.x;
    if (i < n) p[i] = v;
}
__global__ void fill_u32(unsigned* p, unsigned v, long n) {
    long i = (long)blockIdx.x * blockDim.x + threadIdx.x;
    if (i < n) p[i] = v;
}

// ================== register-tiled fp32 GEMM ==================
// 64x64 block tile, BK=16, 256 threads, 4x4 outputs per thread.
// NT=false: C[M,N] = scale*A[M,K]@B[K,N] (+bias) (+addsrc)
// NT=true : B is [N,K] row-major  (C = A @ B^T)
#define BM 64
#define BN 64
#define BK 16
#define LDT 68   // padded LDS row stride (floats); 68*4 % 16 == 0 keeps float4 alignment

template <bool NT>
__global__ __launch_bounds__(256) void gemm_rt(const float* __restrict__ A, const float* __restrict__ B,
                                               const float* __restrict__ bias, const float* __restrict__ addsrc,
                                               float* __restrict__ C, int M, int N, int K, float scale) {
    __shared__ float As[BK][LDT];   // As[kk][row]   (k-major)
    __shared__ float Bs[BK][LDT];   // Bs[kk][col]
    int t  = threadIdx.x;          // 0..255
    int tx = t & 15;               // col group
    int ty = t >> 4;               // row group
    int rowBase = blockIdx.y * BM;
    int colBase = blockIdx.x * BN;

    float acc[4][4] = {};

    for (int k0 = 0; k0 < K; k0 += BK) {
        // ---- load A tile (64 rows x 16 k) -> As[kk][row]
        {
            int kk = t & 15;
            int r0 = t >> 4;
            int ka = k0 + kk;
            bool kok = ka < K;
#pragma unroll
            for (int i = 0; i < 4; i++) {
                int row = r0 + 16 * i;
                int gr = rowBase + row;
                As[kk][row] = (kok && gr < M) ? A[(long)gr * K + ka] : 0.f;
            }
        }
        // ---- load B tile -> Bs[kk][col]
        if (!NT) {
            int col = t & 63;
            int kb0 = t >> 6;       // 0..3
            int gc = colBase + col;
            bool cok = gc < N;
#pragma unroll
            for (int i = 0; i < 4; i++) {
                int kk = kb0 + 4 * i;
                int kb = k0 + kk;
                Bs[kk][col] = (cok && kb < K) ? B[(long)kb * N + gc] : 0.f;
            }
        } else {
            int kk = t & 15;
            int c0 = t >> 4;
            int kb = k0 + kk;
            bool kok = kb < K;
#pragma unroll
            for (int i = 0; i < 4; i++) {
                int col = c0 + 16 * i;
                int gc = colBase + col;
                Bs[kk][col] = (kok && gc < N) ? B[(long)gc * K + kb] : 0.f;
            }
        }
        __syncthreads();

#pragma unroll
        for (int kk = 0; kk < BK; kk++) {
            float4 a = *(const float4*)&As[kk][4 * ty];
            float4 b = *(const float4*)&Bs[kk][4 * tx];
            float av[4] = {a.x, a.y, a.z, a.w};
            float bv[4] = {b.x, b.y, b.z, b.w};
#pragma unroll
            for (int i = 0; i < 4; i++)
#pragma unroll
                for (int j = 0; j < 4; j++)
                    acc[i][j] = fmaf(av[i], bv[j], acc[i][j]);
        }
        __syncthreads();
    }

#pragma unroll
    for (int i = 0; i < 4; i++) {
        int gr = rowBase + 4 * ty + i;
        if (gr >= M) continue;
#pragma unroll
        for (int j = 0; j < 4; j++) {
            int gc = colBase + 4 * tx + j;
            if (gc >= N) continue;
            float v = acc[i][j] * scale;
            if (bias) v += bias[gc];
            if (addsrc) v += addsrc[(long)gr * N + gc];
            C[(long)gr * N + gc] = v;
        }
    }
}

// ---------- small 16x16 GEMM (kept for narrow N like N=10) ----------
__global__ void gemm_kernel(const float* __restrict__ A, const float* __restrict__ B,
                            const float* __restrict__ bias, const float* __restrict__ addsrc,
                            float* __restrict__ C, int M, int N, int K, float scale) {
    __shared__ float As[16][17];
    __shared__ float Bs[16][17];
    int tx = threadIdx.x, ty = threadIdx.y;
    int row = blockIdx.y * 16 + ty;
    int col = blockIdx.x * 16 + tx;
    float acc = 0.f;
    for (int k0 = 0; k0 < K; k0 += 16) {
        int ka = k0 + tx;
        As[ty][tx] = (row < M && ka < K) ? A[(long)row * K + ka] : 0.f;
        int kb = k0 + ty;
        Bs[ty][tx] = (kb < K && col < N) ? B[(long)kb * N + col] : 0.f;
        __syncthreads();
#pragma unroll
        for (int kk = 0; kk < 16; kk++) acc += As[ty][kk] * Bs[kk][tx];
        __syncthreads();
    }
    if (row < M && col < N) {
        float v = acc * scale;
        if (bias) v += bias[col];
        if (addsrc) v += addsrc[(long)row * N + col];
        C[(long)row * N + col] = v;
    }
}

// ---------- row softmax over [R, n] ----------
__global__ void softmax_rows(float* __restrict__ S, int n) {
    int row = blockIdx.x;
    float* p = S + (long)row * n;
    __shared__ float red[256];
    int tid = threadIdx.x;
    float m = -1e30f;
    for (int j = tid; j < n; j += 256) m = fmaxf(m, p[j]);
    red[tid] = m; __syncthreads();
    for (int s = 128; s > 0; s >>= 1) { if (tid < s) red[tid] = fmaxf(red[tid], red[tid + s]); __syncthreads(); }
    m = red[0]; __syncthreads();
    float sum = 0.f;
    for (int j = tid; j < n; j += 256) { float e = expf(p[j] - m); p[j] = e; sum += e; }
    red[tid] = sum; __syncthreads();
    for (int s = 128; s > 0; s >>= 1) { if (tid < s) red[tid] += red[tid + s]; __syncthreads(); }
    float inv = 1.0f / red[0];
    for (int j = tid; j < n; j += 256) p[j] *= inv;
}

// ---------- scatter (last write wins, numpy semantics) ----------
__global__ void scatter_init(int* last, const int* __restrict__ com, int B) {
    int i = blockIdx.x * blockDim.x + threadIdx.x;
    if (i < B) last[com[i]] = -1;
}
__global__ void scatter_max(int* last, const int* __restrict__ com, int B) {
    int i = blockIdx.x * blockDim.x + threadIdx.x;
    if (i < B) atomicMax(&last[com[i]], i);
}
__global__ void scatter_write(const int* __restrict__ last, const int* __restrict__ com,
                              const float* __restrict__ fused, float* __restrict__ x, int B, int D) {
    int i = blockIdx.x;
    int node = com[i];
    if (last[node] != i) return;
    for (int c = threadIdx.x; c < D; c += blockDim.x)
        x[(long)node * D + c] = fused[(long)i * D + c];
}

// ---------- GAT per-node attention coefficients ----------
__global__ void node_attn_coef(const float* __restrict__ h, const float* __restrict__ a_src,
                               const float* __restrict__ a_dst, float* __restrict__ es,
                               float* __restrict__ ed, int N, int H, int C) {
    int idx = blockIdx.x * blockDim.x + threadIdx.x;
    if (idx >= N * H) return;
    int n = idx / H, hh = idx % H;
    const float* hp = h + (long)n * H * C + (long)hh * C;
    const float* as = a_src + hh * C;
    const float* ad = a_dst + hh * C;
    float s = 0.f, d = 0.f;
    for (int c = 0; c < C; c++) { float v = hp[c]; s += v * as[c]; d += v * ad[c]; }
    es[idx] = s; ed[idx] = d;
}

// ---------- edge passes ----------
__global__ void edge_max_k(const int* __restrict__ src, const int* __restrict__ dst, int E, int N,
                           const float* __restrict__ es, const float* __restrict__ ed,
                           unsigned* __restrict__ m, int H) {
    int eid = blockIdx.x * blockDim.x + threadIdx.x;
    int ET = E + N;
    if (eid >= ET) return;
    int s = eid < E ? src[eid] : eid - E;
    int d = eid < E ? dst[eid] : eid - E;
    for (int h = 0; h < H; h++) {
        float e = leaky(es[s * H + h] + ed[d * H + h]);
        atomicMax(&m[d * H + h], enc_f(e));
    }
}
__global__ void edge_denom_k(const int* __restrict__ src, const int* __restrict__ dst, int E, int N,
                             const float* __restrict__ es, const float* __restrict__ ed,
                             const unsigned* __restrict__ m, float* __restrict__ denom, int H) {
    int eid = blockIdx.x * blockDim.x + threadIdx.x;
    int ET = E + N;
    if (eid >= ET) return;
    int s = eid < E ? src[eid] : eid - E;
    int d = eid < E ? dst[eid] : eid - E;
    for (int h = 0; h < H; h++) {
        float e = leaky(es[s * H + h] + ed[d * H + h]);
        atomicAdd(&denom[d * H + h], expf(e - dec_f(m[d * H + h])));
    }
}
// layer1 aggregate: one block (128 threads) per edge, H=3, C=128
__global__ void edge_agg1(const int* __restrict__ src, const int* __restrict__ dst, int E, int N,
                          const float* __restrict__ es, const float* __restrict__ ed,
                          const unsigned* __restrict__ m, const float* __restrict__ denom,
                          const float* __restrict__ h, float* __restrict__ out) {
    int eid = blockIdx.x;
    int ET = E + N;
    if (eid >= ET) return;
    int tid = threadIdx.x;
    int s = eid < E ? src[eid] : eid - E;
    int d = eid < E ? dst[eid] : eid - E;
    __shared__ float alpha[HEADS];
    if (tid < HEADS) {
        float e = leaky(es[s * HEADS + tid] + ed[d * HEADS + tid]);
        alpha[tid] = expf(e - dec_f(m[d * HEADS + tid])) / (denom[d * HEADS + tid] + 1e-16f);
    }
    __syncthreads();
    const float* hs = h + (long)s * HC1;
    float* od = out + (long)d * HC1;
    for (int j = tid; j < HC1; j += 128)
        atomicAdd(&od[j], hs[j] * alpha[j >> 7]);   // C=128 -> head = j/128
}
// layer2 aggregate: thread per edge, H=1, C=10
__global__ void edge_agg2(const int* __restrict__ src, const int* __restrict__ dst, int E, int N,
                          const float* __restrict__ es, const float* __restrict__ ed,
                          const unsigned* __restrict__ m, const float* __restrict__ denom,
                          const float* __restrict__ h, float* __restrict__ out) {
    int eid = blockIdx.x * blockDim.x + threadIdx.x;
    int ET = E + N;
    if (eid >= ET) return;
    int s = eid < E ? src[eid] : eid - E;
    int d = eid < E ? dst[eid] : eid - E;
    float e = leaky(es[s] + ed[d]);
    float alpha = expf(e - dec_f(m[d])) / (denom[d] + 1e-16f);
    const float* hs = h + (long)s * OUTC;
    float* od = out + (long)d * OUTC;
#pragma unroll
    for (int c = 0; c < OUTC; c++) atomicAdd(&od[c], hs[c] * alpha);
}

// ---------- bias (+ optional ELU), in place ----------
__global__ void bias_act(float* __restrict__ x, const float* __restrict__ bias, long total, int N, int do_elu) {
    long i = (long)blockIdx.x * blockDim.x + threadIdx.x;
    if (i >= total) return;
    int j = (int)(i % N);
    float v = x[i] + bias[j];
    if (do_elu) v = v > 0.f ? v : (expf(v) - 1.0f);
    x[i] = v;
}

// ---------- pair scores ----------
__global__ void pair_score(const int* __restrict__ pairs, const float* __restrict__ emb,
                           float* __restrict__ out, int P) {
    int p = blockIdx.x * blockDim.x + threadIdx.x;
    if (p >= P) return;
    int i0 = pairs[2 * p], i1 = pairs[2 * p + 1];
    const float* a = emb + (long)i0 * OUTC;
    const float* b = emb + (long)i1 * OUTC;
    float s = 0.f;
#pragma unroll
    for (int c = 0; c < OUTC; c++) s += a[c] * b[c];
    out[p] = s;
}

extern "C" void kernel_launch(void* const* d_in, const int* in_sizes, int n_in,
                              void* d_out, int out_size, void* d_ws, size_t ws_size,
                              hipStream_t stream) {
    const float* fsub = (const float*)d_in[0];
    const float* fcom = (const float*)d_in[1];
    float*       x    = (float*)d_in[2];          // scatter target (harness restores each launch)
    const int*   com  = (const int*)d_in[3];
    const int*   ei   = (const int*)d_in[4];
    const int*   pidx = (const int*)d_in[5];
    const float* Wq = (const float*)d_in[6];  const float* bq = (const float*)d_in[7];
    const float* Wk = (const float*)d_in[8];  const float* bk = (const float*)d_in[9];
    const float* Wv = (const float*)d_in[10]; const float* bv = (const float*)d_in[11];
    const float* Wf = (const float*)d_in[12]; const float* bf = (const float*)d_in[13];
    const float* W1 = (const float*)d_in[14];
    const float* as1 = (const float*)d_in[15]; const float* ad1 = (const float*)d_in[16];
    const float* b1 = (const float*)d_in[17];
    const float* W2 = (const float*)d_in[18];
    const float* as2 = (const float*)d_in[19]; const float* ad2 = (const float*)d_in[20];
    const float* b2 = (const float*)d_in[21];
    float* out = (float*)d_out;

    const int* src = ei;
    const int* dst = ei + NE;

    char* ws = (char*)d_ws;
    // ---- phase 1 layout (attention) ----
    float* S    = (float*)(ws + 0);          // 4096*4096*4       = 67,108,864
    float* q    = (float*)(ws + 67108864);   // 4096*300*4        =  4,915,200
    float* kbuf = (float*)(ws + 72024064);
    float* vbuf = (float*)(ws + 76939264);
    float* attn = (float*)(ws + 81854464);
    float* fus  = (float*)(ws + 86769664);   // ends 91,684,864
    // ---- phase 2 layout (GAT) — reuses offset 0 after scatter ----
    float*    h1   = (float*)(ws + 0);          // 50000*384*4 = 76,800,000
    float*    out1 = (float*)(ws + 76800000);   // 76,800,000  -> ends 153,600,000
    char*     sm   = ws + 153600000;
    float*    es1  = (float*)(sm);               sm += 600000;   // 50000*3*4
    float*    ed1  = (float*)(sm);               sm += 600000;
    unsigned* m1   = (unsigned*)(sm);            sm += 600000;
    float*    den1 = (float*)(sm);               sm += 600000;
    float*    h2   = (float*)(sm);               sm += 2000000;  // 50000*10*4
    float*    embp = (float*)(sm);               sm += 2000000;
    float*    es2  = (float*)(sm);               sm += 200000;
    float*    ed2  = (float*)(sm);               sm += 200000;
    unsigned* m2   = (unsigned*)(sm);            sm += 200000;
    float*    den2 = (float*)(sm);               sm += 200000;
    int*      last = (int*)(sm);                 sm += 200000;   // total ~158.9 MB

    const float inv_sqrt_d = 1.0f / sqrtf((float)FEAT);

    // ===== 1. cross attention =====
    hipLaunchKernelGGL((gemm_rt<false>), dim3(cdiv(FEAT,BN), cdiv(BP,BM)), dim3(256), 0, stream,
                       fsub, Wq, bq, nullptr, q, BP, FEAT, FEAT, 1.0f);
    hipLaunchKernelGGL((gemm_rt<false>), dim3(cdiv(FEAT,BN), cdiv(BP,BM)), dim3(256), 0, stream,
                       fcom, Wk, bk, nullptr, kbuf, BP, FEAT, FEAT, 1.0f);
    hipLaunchKernelGGL((gemm_rt<false>), dim3(cdiv(FEAT,BN), cdiv(BP,BM)), dim3(256), 0, stream,
                       fcom, Wv, bv, nullptr, vbuf, BP, FEAT, FEAT, 1.0f);
    // S = (q @ k^T) * inv_sqrt_d
    hipLaunchKernelGGL((gemm_rt<true>), dim3(cdiv(BP,BN), cdiv(BP,BM)), dim3(256), 0, stream,
                       q, kbuf, nullptr, nullptr, S, BP, BP, FEAT, inv_sqrt_d);
    hipLaunchKernelGGL(softmax_rows, dim3(BP), dim3(256), 0, stream, S, BP);
    // attn = fsub + S @ v
    hipLaunchKernelGGL((gemm_rt<false>), dim3(cdiv(FEAT,BN), cdiv(BP,BM)), dim3(256), 0, stream,
                       S, vbuf, nullptr, fsub, attn, BP, FEAT, BP, 1.0f);
    // fused = attn @ Wf + bf
    hipLaunchKernelGGL((gemm_rt<false>), dim3(cdiv(FEAT,BN), cdiv(BP,BM)), dim3(256), 0, stream,
                       attn, Wf, bf, nullptr, fus, BP, FEAT, FEAT, 1.0f);

    // ===== 2. scatter fused into x (last write wins) =====
    hipLaunchKernelGGL(scatter_init, dim3(cdiv(BP,256)), dim3(256), 0, stream, last, com, BP);
    hipLaunchKernelGGL(scatter_max,  dim3(cdiv(BP,256)), dim3(256), 0, stream, last, com, BP);
    hipLaunchKernelGGL(scatter_write, dim3(BP), dim3(128), 0, stream, last, com, fus, x, BP, FEAT);

    // ===== 3. GAT layer 1 =====
    hipLaunchKernelGGL((gemm_rt<false>), dim3(cdiv(HC1,BN), cdiv(NN,BM)), dim3(256), 0, stream,
                       x, W1, nullptr, nullptr, h1, NN, HC1, FEAT, 1.0f);
    hipLaunchKernelGGL(node_attn_coef, dim3(cdiv(NN*HEADS,256)), dim3(256), 0, stream,
                       h1, as1, ad1, es1, ed1, NN, HEADS, HID);
    hipLaunchKernelGGL(fill_u32, dim3(cdiv(NN*HEADS,256)), dim3(256), 0, stream, m1, 0u, (long)NN*HEADS);
    hipLaunchKernelGGL(fill_f32, dim3(cdiv(NN*HEADS,256)), dim3(256), 0, stream, den1, 0.f, (long)NN*HEADS);
    hipLaunchKernelGGL(fill_f32, dim3(cdiv(NN*HC1,256)), dim3(256), 0, stream, out1, 0.f, (long)NN*HC1);
    int ET = NE + NN;
    hipLaunchKernelGGL(edge_max_k,   dim3(cdiv(ET,256)), dim3(256), 0, stream, src, dst, NE, NN, es1, ed1, m1, HEADS);
    hipLaunchKernelGGL(edge_denom_k, dim3(cdiv(ET,256)), dim3(256), 0, stream, src, dst, NE, NN, es1, ed1, m1, den1, HEADS);
    hipLaunchKernelGGL(edge_agg1, dim3(ET), dim3(128), 0, stream, src, dst, NE, NN, es1, ed1, m1, den1, h1, out1);
    // out1 = elu(out1 + b1)
    hipLaunchKernelGGL(bias_act, dim3(cdiv(NN*HC1,256)), dim3(256), 0, stream, out1, b1, (long)NN*HC1, HC1, 1);

    // ===== 4. GAT layer 2 =====
    hipLaunchKernelGGL(gemm_kernel, dim3(cdiv(OUTC,16), cdiv(NN,16)), dim3(16,16), 0, stream,
                       out1, W2, nullptr, nullptr, h2, NN, OUTC, HC1, 1.0f);
    hipLaunchKernelGGL(node_attn_coef, dim3(cdiv(NN,256)), dim3(256), 0, stream,
                       h2, as2, ad2, es2, ed2, NN, 1, OUTC);
    hipLaunchKernelGGL(fill_u32, dim3(cdiv(NN,256)), dim3(256), 0, stream, m2, 0u, (long)NN);
    hipLaunchKernelGGL(fill_f32, dim3(cdiv(NN,256)), dim3(256), 0, stream, den2, 0.f, (long)NN);
    hipLaunchKernelGGL(fill_f32, dim3(cdiv(NN*OUTC,256)), dim3(256), 0, stream, embp, 0.f, (long)NN*OUTC);
    hipLaunchKernelGGL(edge_max_k,   dim3(cdiv(ET,256)), dim3(256), 0, stream, src, dst, NE, NN, es2, ed2, m2, 1);
    hipLaunchKernelGGL(edge_denom_k, dim3(cdiv(ET,256)), dim3(256), 0, stream, src, dst, NE, NN, es2, ed2, m2, den2, 1);
    hipLaunchKernelGGL(edge_agg2, dim3(cdiv(ET,256)), dim3(256), 0, stream, src, dst, NE, NN, es2, ed2, m2, den2, h2, embp);
    // emb = embp + b2
    hipLaunchKernelGGL(bias_act, dim3(cdiv(NN*OUTC,256)), dim3(256), 0, stream, embp, b2, (long)NN*OUTC, OUTC, 0);

    // ===== 5. pair scores =====
    hipLaunchKernelGGL(pair_score, dim3(cdiv(NP,256)), dim3(256), 0, stream, pidx, embp, out, NP);
}

// Round 3
// 1842.418 us; speedup vs baseline: 2.1185x; 1.5181x over previous
//
#include <hip/hip_runtime.h>
#include <math.h>

#define NN      50000      // N_NODES
#define BP      4096       // N_PAIRS_MAP
#define NE      500000     // N_EDGES
#define NP      1000000    // N_SCORE_PAIRS
#define FEAT    300
#define HID     128
#define HEADS   3
#define OUTC    10
#define HC1     (HEADS*HID)   // 384
#define NEG_SLOPE 0.2f
#define ET      (NE + NN)     // edges incl self-loops

static inline int cdiv(int a, int b) { return (a + b - 1) / b; }

__device__ inline float leaky(float x) { return x > 0.f ? x : NEG_SLOPE * x; }

// ================== register-tiled fp32 GEMM ==================
// 64x64 block tile, BK=16, 256 threads, 4x4 outputs per thread.
// NT=false: C[M,N] = scale*A[M,K]@B[K,N] (+bias) (+addsrc)
// NT=true : B is [N,K] row-major  (C = A @ B^T)
#define BM 64
#define BN 64
#define BK 16
#define LDT 68   // padded LDS row stride (floats); 68*4 % 16 == 0 keeps float4 alignment

template <bool NT>
__global__ __launch_bounds__(256) void gemm_rt(const float* __restrict__ A, const float* __restrict__ B,
                                               const float* __restrict__ bias, const float* __restrict__ addsrc,
                                               float* __restrict__ C, int M, int N, int K, float scale) {
    __shared__ float As[BK][LDT];
    __shared__ float Bs[BK][LDT];
    int t  = threadIdx.x;
    int tx = t & 15;
    int ty = t >> 4;
    int rowBase = blockIdx.y * BM;
    int colBase = blockIdx.x * BN;

    float acc[4][4] = {};

    for (int k0 = 0; k0 < K; k0 += BK) {
        {
            int kk = t & 15;
            int r0 = t >> 4;
            int ka = k0 + kk;
            bool kok = ka < K;
#pragma unroll
            for (int i = 0; i < 4; i++) {
                int row = r0 + 16 * i;
                int gr = rowBase + row;
                As[kk][row] = (kok && gr < M) ? A[(long)gr * K + ka] : 0.f;
            }
        }
        if (!NT) {
            int col = t & 63;
            int kb0 = t >> 6;
            int gc = colBase + col;
            bool cok = gc < N;
#pragma unroll
            for (int i = 0; i < 4; i++) {
                int kk = kb0 + 4 * i;
                int kb = k0 + kk;
                Bs[kk][col] = (cok && kb < K) ? B[(long)kb * N + gc] : 0.f;
            }
        } else {
            int kk = t & 15;
            int c0 = t >> 4;
            int kb = k0 + kk;
            bool kok = kb < K;
#pragma unroll
            for (int i = 0; i < 4; i++) {
                int col = c0 + 16 * i;
                int gc = colBase + col;
                Bs[kk][col] = (kok && gc < N) ? B[(long)gc * K + kb] : 0.f;
            }
        }
        __syncthreads();

#pragma unroll
        for (int kk = 0; kk < BK; kk++) {
            float4 a = *(const float4*)&As[kk][4 * ty];
            float4 b = *(const float4*)&Bs[kk][4 * tx];
            float av[4] = {a.x, a.y, a.z, a.w};
            float bv[4] = {b.x, b.y, b.z, b.w};
#pragma unroll
            for (int i = 0; i < 4; i++)
#pragma unroll
                for (int j = 0; j < 4; j++)
                    acc[i][j] = fmaf(av[i], bv[j], acc[i][j]);
        }
        __syncthreads();
    }

#pragma unroll
    for (int i = 0; i < 4; i++) {
        int gr = rowBase + 4 * ty + i;
        if (gr >= M) continue;
#pragma unroll
        for (int j = 0; j < 4; j++) {
            int gc = colBase + 4 * tx + j;
            if (gc >= N) continue;
            float v = acc[i][j] * scale;
            if (bias) v += bias[gc];
            if (addsrc) v += addsrc[(long)gr * N + gc];
            C[(long)gr * N + gc] = v;
        }
    }
}

// ---------- row softmax over [R, n] ----------
__global__ void softmax_rows(float* __restrict__ S, int n) {
    int row = blockIdx.x;
    float* p = S + (long)row * n;
    __shared__ float red[256];
    int tid = threadIdx.x;
    float m = -1e30f;
    for (int j = tid; j < n; j += 256) m = fmaxf(m, p[j]);
    red[tid] = m; __syncthreads();
    for (int s = 128; s > 0; s >>= 1) { if (tid < s) red[tid] = fmaxf(red[tid], red[tid + s]); __syncthreads(); }
    m = red[0]; __syncthreads();
    float sum = 0.f;
    for (int j = tid; j < n; j += 256) { float e = expf(p[j] - m); p[j] = e; sum += e; }
    red[tid] = sum; __syncthreads();
    for (int s = 128; s > 0; s >>= 1) { if (tid < s) red[tid] += red[tid + s]; __syncthreads(); }
    float inv = 1.0f / red[0];
    for (int j = tid; j < n; j += 256) p[j] *= inv;
}

// ---------- scatter (last write wins, numpy semantics) ----------
__global__ void scatter_init(int* last, const int* __restrict__ com, int B) {
    int i = blockIdx.x * blockDim.x + threadIdx.x;
    if (i < B) last[com[i]] = -1;
}
__global__ void scatter_max(int* last, const int* __restrict__ com, int B) {
    int i = blockIdx.x * blockDim.x + threadIdx.x;
    if (i < B) atomicMax(&last[com[i]], i);
}
__global__ void scatter_write(const int* __restrict__ last, const int* __restrict__ com,
                              const float* __restrict__ fused, float* __restrict__ x, int B, int D) {
    int i = blockIdx.x;
    int node = com[i];
    if (last[node] != i) return;
    for (int c = threadIdx.x; c < D; c += blockDim.x)
        x[(long)node * D + c] = fused[(long)i * D + c];
}

// ---------- GAT per-node attention coefficients ----------
__global__ void node_attn_coef(const float* __restrict__ h, const float* __restrict__ a_src,
                               const float* __restrict__ a_dst, float* __restrict__ es,
                               float* __restrict__ ed, int N, int H, int C) {
    int idx = blockIdx.x * blockDim.x + threadIdx.x;
    if (idx >= N * H) return;
    int n = idx / H, hh = idx % H;
    const float* hp = h + (long)n * H * C + (long)hh * C;
    const float* as = a_src + hh * C;
    const float* ad = a_dst + hh * C;
    float s = 0.f, d = 0.f;
    for (int c = 0; c < C; c++) { float v = hp[c]; s += v * as[c]; d += v * ad[c]; }
    es[idx] = s; ed[idx] = d;
}

// ================== CSR build ==================
__global__ void deg_init(int* deg, int n) {   // start at 1: self-loop
    int i = blockIdx.x * blockDim.x + threadIdx.x;
    if (i < n) deg[i] = 1;
}
__global__ void deg_count(const int* __restrict__ dst, int* deg, int E) {
    int e = blockIdx.x * blockDim.x + threadIdx.x;
    if (e < E) atomicAdd(&deg[dst[e]], 1);
}
#define SCAN_BLOCK 1024
__global__ __launch_bounds__(SCAN_BLOCK) void scan_rowptr(const int* __restrict__ deg, int* __restrict__ rowptr, int n) {
    __shared__ int tmp[SCAN_BLOCK];
    __shared__ int carry;
    int tid = threadIdx.x;
    if (tid == 0) carry = 0;
    __syncthreads();
    for (int base = 0; base < n; base += SCAN_BLOCK) {
        int i = base + tid;
        int v = (i < n) ? deg[i] : 0;
        tmp[tid] = v; __syncthreads();
        for (int off = 1; off < SCAN_BLOCK; off <<= 1) {
            int t2 = (tid >= off) ? tmp[tid - off] : 0;
            __syncthreads();
            tmp[tid] += t2;
            __syncthreads();
        }
        int incl = tmp[tid];
        if (i < n) rowptr[i + 1] = carry + incl;
        __syncthreads();
        if (tid == SCAN_BLOCK - 1) carry += incl;
        __syncthreads();
    }
    if (tid == 0) rowptr[0] = 0;
}
__global__ void copy_i32(const int* __restrict__ a, int* __restrict__ b, int n) {
    int i = blockIdx.x * blockDim.x + threadIdx.x;
    if (i < n) b[i] = a[i];
}
__global__ void csr_fill(const int* __restrict__ src, const int* __restrict__ dst,
                         int* cursor, int* __restrict__ csr_src, int E) {
    int e = blockIdx.x * blockDim.x + threadIdx.x;
    if (e >= E) return;
    int slot = atomicAdd(&cursor[dst[e]], 1);
    csr_src[slot] = src[e];
}
__global__ void csr_fill_loops(int* cursor, int* __restrict__ csr_src, int n) {
    int i = blockIdx.x * blockDim.x + threadIdx.x;
    if (i >= n) return;
    int slot = atomicAdd(&cursor[i], 1);
    csr_src[slot] = i;
}

// ---------- segment max + denom per (node, head), gather over CSR ----------
__global__ void csr_maxden(const int* __restrict__ rowptr, const int* __restrict__ csr_src,
                           const float* __restrict__ es, const float* __restrict__ ed,
                           float* __restrict__ m, float* __restrict__ den, int N, int H) {
    int idx = blockIdx.x * blockDim.x + threadIdx.x;
    if (idx >= N * H) return;
    int d = idx / H, h = idx - d * H;
    float edv = ed[idx];
    int b = rowptr[d], e = rowptr[d + 1];
    float mm = -1e30f;
    for (int s0 = b; s0 < e; s0++) {
        int s = csr_src[s0];
        mm = fmaxf(mm, leaky(es[s * H + h] + edv));
    }
    float dn = 0.f;
    for (int s0 = b; s0 < e; s0++) {
        int s = csr_src[s0];
        dn += expf(leaky(es[s * H + h] + edv) - mm);
    }
    m[idx] = mm;
    den[idx] = dn;
}

// ---------- layer-1 aggregate + bias + ELU + (row @ W2) fused ----------
// one block of 128 threads per destination node; channels t, t+128, t+256.
__global__ __launch_bounds__(128) void csr_agg1_fused(
    const int* __restrict__ rowptr, const int* __restrict__ csr_src,
    const float* __restrict__ es, const float* __restrict__ ed,
    const float* __restrict__ m1, const float* __restrict__ den1,
    const float* __restrict__ h1, const float* __restrict__ b1,
    const float* __restrict__ W2, float* __restrict__ h2, int N)
{
    int d = blockIdx.x;
    int t = threadIdx.x;
    __shared__ float row[HC1];           // 384 floats
    __shared__ float part[128][OUTC + 1];

    int b = rowptr[d], e = rowptr[d + 1];
    float ed0 = ed[d * 3 + 0], ed1 = ed[d * 3 + 1], ed2 = ed[d * 3 + 2];
    float mm0 = m1[d * 3 + 0], mm1 = m1[d * 3 + 1], mm2 = m1[d * 3 + 2];
    float i0 = 1.f / (den1[d * 3 + 0] + 1e-16f);
    float i1 = 1.f / (den1[d * 3 + 1] + 1e-16f);
    float i2 = 1.f / (den1[d * 3 + 2] + 1e-16f);

    float a0 = 0.f, a1 = 0.f, a2 = 0.f;
    for (int s0 = b; s0 < e; s0++) {
        int s = csr_src[s0];
        float e0 = es[s * 3 + 0], e1 = es[s * 3 + 1], e2 = es[s * 3 + 2];
        float al0 = expf(leaky(e0 + ed0) - mm0) * i0;
        float al1 = expf(leaky(e1 + ed1) - mm1) * i1;
        float al2 = expf(leaky(e2 + ed2) - mm2) * i2;
        const float* hp = h1 + (long)s * HC1;
        a0 = fmaf(hp[t],       al0, a0);
        a1 = fmaf(hp[t + 128], al1, a1);
        a2 = fmaf(hp[t + 256], al2, a2);
    }
    float v;
    v = a0 + b1[t];       row[t]       = v > 0.f ? v : expf(v) - 1.f;
    v = a1 + b1[t + 128]; row[t + 128] = v > 0.f ? v : expf(v) - 1.f;
    v = a2 + b1[t + 256]; row[t + 256] = v > 0.f ? v : expf(v) - 1.f;
    __syncthreads();

    // h2[d] = row @ W2  (W2 is [384,10])
    float pc[OUTC];
#pragma unroll
    for (int c = 0; c < OUTC; c++) pc[c] = 0.f;
    for (int k = t; k < HC1; k += 128) {
        float rv = row[k];
        const float* w = W2 + (long)k * OUTC;
#pragma unroll
        for (int c = 0; c < OUTC; c++) pc[c] = fmaf(rv, w[c], pc[c]);
    }
#pragma unroll
    for (int c = 0; c < OUTC; c++) part[t][c] = pc[c];
    __syncthreads();
    for (int off = 64; off > 0; off >>= 1) {
        if (t < off) {
#pragma unroll
            for (int c = 0; c < OUTC; c++) part[t][c] += part[t + off][c];
        }
        __syncthreads();
    }
    if (t < OUTC) h2[(long)d * OUTC + t] = part[0][t];
}

// ---------- layer-2 aggregate + bias, thread per (node, channel) ----------
__global__ void csr_agg2(const int* __restrict__ rowptr, const int* __restrict__ csr_src,
                         const float* __restrict__ es, const float* __restrict__ ed,
                         const float* __restrict__ m2, const float* __restrict__ den2,
                         const float* __restrict__ h2, const float* __restrict__ b2,
                         float* __restrict__ emb, int N)
{
    int idx = blockIdx.x * blockDim.x + threadIdx.x;
    if (idx >= N * OUTC) return;
    int d = idx / OUTC, c = idx - d * OUTC;
    float edv = ed[d], mm = m2[d], inv = 1.f / (den2[d] + 1e-16f);
    int b = rowptr[d], e = rowptr[d + 1];
    float acc = 0.f;
    for (int s0 = b; s0 < e; s0++) {
        int s = csr_src[s0];
        float al = expf(leaky(es[s] + edv) - mm) * inv;
        acc = fmaf(h2[(long)s * OUTC + c], al, acc);
    }
    emb[idx] = acc + b2[c];
}

// ---------- pair scores ----------
__global__ void pair_score(const int* __restrict__ pairs, const float* __restrict__ emb,
                           float* __restrict__ out, int P) {
    int p = blockIdx.x * blockDim.x + threadIdx.x;
    if (p >= P) return;
    int i0 = pairs[2 * p], i1 = pairs[2 * p + 1];
    const float* a = emb + (long)i0 * OUTC;
    const float* b = emb + (long)i1 * OUTC;
    float s = 0.f;
#pragma unroll
    for (int c = 0; c < OUTC; c++) s += a[c] * b[c];
    out[p] = s;
}

extern "C" void kernel_launch(void* const* d_in, const int* in_sizes, int n_in,
                              void* d_out, int out_size, void* d_ws, size_t ws_size,
                              hipStream_t stream) {
    const float* fsub = (const float*)d_in[0];
    const float* fcom = (const float*)d_in[1];
    float*       x    = (float*)d_in[2];          // scatter target (harness restores each launch)
    const int*   com  = (const int*)d_in[3];
    const int*   ei   = (const int*)d_in[4];
    const int*   pidx = (const int*)d_in[5];
    const float* Wq = (const float*)d_in[6];  const float* bq = (const float*)d_in[7];
    const float* Wk = (const float*)d_in[8];  const float* bk = (const float*)d_in[9];
    const float* Wv = (const float*)d_in[10]; const float* bv = (const float*)d_in[11];
    const float* Wf = (const float*)d_in[12]; const float* bf = (const float*)d_in[13];
    const float* W1 = (const float*)d_in[14];
    const float* as1 = (const float*)d_in[15]; const float* ad1 = (const float*)d_in[16];
    const float* b1 = (const float*)d_in[17];
    const float* W2 = (const float*)d_in[18];
    const float* as2 = (const float*)d_in[19]; const float* ad2 = (const float*)d_in[20];
    const float* b2 = (const float*)d_in[21];
    float* out = (float*)d_out;

    const int* src = ei;
    const int* dst = ei + NE;

    char* ws = (char*)d_ws;
    // ---- phase 1 (attention): 0 .. 91.7 MB ----
    float* S    = (float*)(ws + 0);          // 4096*4096*4 = 67,108,864
    float* q    = (float*)(ws + 67108864);
    float* kbuf = (float*)(ws + 72024064);
    float* vbuf = (float*)(ws + 76939264);
    float* attn = (float*)(ws + 81854464);
    float* fus  = (float*)(ws + 86769664);   // ends 91,684,864
    // ---- phase 2 (GAT): h1 overlays S after attention; small bufs at 92 MB+ ----
    float*    h1   = (float*)(ws + 0);          // 50000*384*4 = 76,800,000
    float*    es1  = (float*)(ws + 92000000);   // 600,000
    float*    ed1  = (float*)(ws + 92600000);
    float*    m1   = (float*)(ws + 93200000);
    float*    den1 = (float*)(ws + 93800000);
    float*    es2  = (float*)(ws + 94400000);   // 200,000
    float*    ed2  = (float*)(ws + 94600000);
    float*    m2   = (float*)(ws + 94800000);
    float*    den2 = (float*)(ws + 95000000);
    float*    h2   = (float*)(ws + 95200000);   // 2,000,000
    float*    embp = (float*)(ws + 97200000);   // 2,000,000
    int*      last = (int*)(ws + 99200000);     // 200,000
    int*      deg  = (int*)(ws + 99400000);     // 200,000
    int*      curs = (int*)(ws + 99600000);     // 200,000
    int*      rowp = (int*)(ws + 99800000);     // 200,016
    int*      csrc = (int*)(ws + 100000016);    // 2,200,000 -> ends ~102.2 MB

    const float inv_sqrt_d = 1.0f / sqrtf((float)FEAT);

    // ===== 1. cross attention =====
    hipLaunchKernelGGL((gemm_rt<false>), dim3(cdiv(FEAT,BN), cdiv(BP,BM)), dim3(256), 0, stream,
                       fsub, Wq, bq, nullptr, q, BP, FEAT, FEAT, 1.0f);
    hipLaunchKernelGGL((gemm_rt<false>), dim3(cdiv(FEAT,BN), cdiv(BP,BM)), dim3(256), 0, stream,
                       fcom, Wk, bk, nullptr, kbuf, BP, FEAT, FEAT, 1.0f);
    hipLaunchKernelGGL((gemm_rt<false>), dim3(cdiv(FEAT,BN), cdiv(BP,BM)), dim3(256), 0, stream,
                       fcom, Wv, bv, nullptr, vbuf, BP, FEAT, FEAT, 1.0f);
    hipLaunchKernelGGL((gemm_rt<true>), dim3(cdiv(BP,BN), cdiv(BP,BM)), dim3(256), 0, stream,
                       q, kbuf, nullptr, nullptr, S, BP, BP, FEAT, inv_sqrt_d);
    hipLaunchKernelGGL(softmax_rows, dim3(BP), dim3(256), 0, stream, S, BP);
    hipLaunchKernelGGL((gemm_rt<false>), dim3(cdiv(FEAT,BN), cdiv(BP,BM)), dim3(256), 0, stream,
                       S, vbuf, nullptr, fsub, attn, BP, FEAT, BP, 1.0f);
    hipLaunchKernelGGL((gemm_rt<false>), dim3(cdiv(FEAT,BN), cdiv(BP,BM)), dim3(256), 0, stream,
                       attn, Wf, bf, nullptr, fus, BP, FEAT, FEAT, 1.0f);

    // ===== 2. scatter fused into x (last write wins) =====
    hipLaunchKernelGGL(scatter_init, dim3(cdiv(BP,256)), dim3(256), 0, stream, last, com, BP);
    hipLaunchKernelGGL(scatter_max,  dim3(cdiv(BP,256)), dim3(256), 0, stream, last, com, BP);
    hipLaunchKernelGGL(scatter_write, dim3(BP), dim3(128), 0, stream, last, com, fus, x, BP, FEAT);

    // ===== 3. CSR build (dst-indexed, incl self-loops) =====
    hipLaunchKernelGGL(deg_init,  dim3(cdiv(NN,256)), dim3(256), 0, stream, deg, NN);
    hipLaunchKernelGGL(deg_count, dim3(cdiv(NE,256)), dim3(256), 0, stream, dst, deg, NE);
    hipLaunchKernelGGL(scan_rowptr, dim3(1), dim3(SCAN_BLOCK), 0, stream, deg, rowp, NN);
    hipLaunchKernelGGL(copy_i32, dim3(cdiv(NN,256)), dim3(256), 0, stream, rowp, curs, NN);
    hipLaunchKernelGGL(csr_fill, dim3(cdiv(NE,256)), dim3(256), 0, stream, src, dst, curs, csrc, NE);
    hipLaunchKernelGGL(csr_fill_loops, dim3(cdiv(NN,256)), dim3(256), 0, stream, curs, csrc, NN);

    // ===== 4. GAT layer 1 (+fused bias/ELU and @W2 projection) =====
    hipLaunchKernelGGL((gemm_rt<false>), dim3(cdiv(HC1,BN), cdiv(NN,BM)), dim3(256), 0, stream,
                       x, W1, nullptr, nullptr, h1, NN, HC1, FEAT, 1.0f);
    hipLaunchKernelGGL(node_attn_coef, dim3(cdiv(NN*HEADS,256)), dim3(256), 0, stream,
                       h1, as1, ad1, es1, ed1, NN, HEADS, HID);
    hipLaunchKernelGGL(csr_maxden, dim3(cdiv(NN*HEADS,256)), dim3(256), 0, stream,
                       rowp, csrc, es1, ed1, m1, den1, NN, HEADS);
    hipLaunchKernelGGL(csr_agg1_fused, dim3(NN), dim3(128), 0, stream,
                       rowp, csrc, es1, ed1, m1, den1, h1, b1, W2, h2, NN);

    // ===== 5. GAT layer 2 =====
    hipLaunchKernelGGL(node_attn_coef, dim3(cdiv(NN,256)), dim3(256), 0, stream,
                       h2, as2, ad2, es2, ed2, NN, 1, OUTC);
    hipLaunchKernelGGL(csr_maxden, dim3(cdiv(NN,256)), dim3(256), 0, stream,
                       rowp, csrc, es2, ed2, m2, den2, NN, 1);
    hipLaunchKernelGGL(csr_agg2, dim3(cdiv(NN*OUTC,256)), dim3(256), 0, stream,
                       rowp, csrc, es2, ed2, m2, den2, h2, b2, embp, NN);

    // ===== 6. pair scores =====
    hipLaunchKernelGGL(pair_score, dim3(cdiv(NP,256)), dim3(256), 0, stream, pidx, embp, out, NP);
}

// Round 4
// 1504.255 us; speedup vs baseline: 2.5947x; 1.2248x over previous
//
#include <hip/hip_runtime.h>
#include <math.h>

#define NN      50000      // N_NODES
#define BP      4096       // N_PAIRS_MAP
#define NE      500000     // N_EDGES
#define NP      1000000    // N_SCORE_PAIRS
#define FEAT    300
#define HID     128
#define HEADS   3
#define OUTC    10
#define HC1     (HEADS*HID)   // 384
#define NEG_SLOPE 0.2f

static inline int cdiv(int a, int b) { return (a + b - 1) / b; }

__device__ inline float leaky(float x) { return x > 0.f ? x : NEG_SLOPE * x; }

// ================== register-tiled fp32 GEMM ==================
// 64x64 block tile, BK=16, 256 threads, 4x4 outputs per thread.
#define BM 64
#define BN 64
#define BK 16
#define LDT 68

template <bool NT>
__global__ __launch_bounds__(256) void gemm_rt(const float* __restrict__ A, const float* __restrict__ B,
                                               const float* __restrict__ bias, const float* __restrict__ addsrc,
                                               float* __restrict__ C, int M, int N, int K, float scale) {
    __shared__ float As[BK][LDT];
    __shared__ float Bs[BK][LDT];
    int t  = threadIdx.x;
    int tx = t & 15;
    int ty = t >> 4;
    int rowBase = blockIdx.y * BM;
    int colBase = blockIdx.x * BN;

    float acc[4][4] = {};

    for (int k0 = 0; k0 < K; k0 += BK) {
        {
            int kk = t & 15;
            int r0 = t >> 4;
            int ka = k0 + kk;
            bool kok = ka < K;
#pragma unroll
            for (int i = 0; i < 4; i++) {
                int row = r0 + 16 * i;
                int gr = rowBase + row;
                As[kk][row] = (kok && gr < M) ? A[(long)gr * K + ka] : 0.f;
            }
        }
        if (!NT) {
            int col = t & 63;
            int kb0 = t >> 6;
            int gc = colBase + col;
            bool cok = gc < N;
#pragma unroll
            for (int i = 0; i < 4; i++) {
                int kk = kb0 + 4 * i;
                int kb = k0 + kk;
                Bs[kk][col] = (cok && kb < K) ? B[(long)kb * N + gc] : 0.f;
            }
        } else {
            int kk = t & 15;
            int c0 = t >> 4;
            int kb = k0 + kk;
            bool kok = kb < K;
#pragma unroll
            for (int i = 0; i < 4; i++) {
                int col = c0 + 16 * i;
                int gc = colBase + col;
                Bs[kk][col] = (kok && gc < N) ? B[(long)gc * K + kb] : 0.f;
            }
        }
        __syncthreads();

#pragma unroll
        for (int kk = 0; kk < BK; kk++) {
            float4 a = *(const float4*)&As[kk][4 * ty];
            float4 b = *(const float4*)&Bs[kk][4 * tx];
            float av[4] = {a.x, a.y, a.z, a.w};
            float bv[4] = {b.x, b.y, b.z, b.w};
#pragma unroll
            for (int i = 0; i < 4; i++)
#pragma unroll
                for (int j = 0; j < 4; j++)
                    acc[i][j] = fmaf(av[i], bv[j], acc[i][j]);
        }
        __syncthreads();
    }

#pragma unroll
    for (int i = 0; i < 4; i++) {
        int gr = rowBase + 4 * ty + i;
        if (gr >= M) continue;
#pragma unroll
        for (int j = 0; j < 4; j++) {
            int gc = colBase + 4 * tx + j;
            if (gc >= N) continue;
            float v = acc[i][j] * scale;
            if (bias) v += bias[gc];
            if (addsrc) v += addsrc[(long)gr * N + gc];
            C[(long)gr * N + gc] = v;
        }
    }
}

// ================== split-K fp32 GEMM (A,B row-major) ==================
// part[z][M][N] partial sums over K-chunk z of size KC.
__global__ __launch_bounds__(256) void gemm_splitk(const float* __restrict__ A, const float* __restrict__ B,
                                                   float* __restrict__ part, int M, int N, int K, int KC) {
    __shared__ float As[BK][LDT];
    __shared__ float Bs[BK][LDT];
    int t  = threadIdx.x;
    int tx = t & 15;
    int ty = t >> 4;
    int rowBase = blockIdx.y * BM;
    int colBase = blockIdx.x * BN;
    int kbeg = blockIdx.z * KC;
    int kend = min(K, kbeg + KC);

    float acc[4][4] = {};

    for (int k0 = kbeg; k0 < kend; k0 += BK) {
        {
            int kk = t & 15;
            int r0 = t >> 4;
            int ka = k0 + kk;
            bool kok = ka < kend;
#pragma unroll
            for (int i = 0; i < 4; i++) {
                int row = r0 + 16 * i;
                int gr = rowBase + row;
                As[kk][row] = (kok && gr < M) ? A[(long)gr * K + ka] : 0.f;
            }
        }
        {
            int col = t & 63;
            int kb0 = t >> 6;
            int gc = colBase + col;
            bool cok = gc < N;
#pragma unroll
            for (int i = 0; i < 4; i++) {
                int kk = kb0 + 4 * i;
                int kb = k0 + kk;
                Bs[kk][col] = (cok && kb < kend) ? B[(long)kb * N + gc] : 0.f;
            }
        }
        __syncthreads();

#pragma unroll
        for (int kk = 0; kk < BK; kk++) {
            float4 a = *(const float4*)&As[kk][4 * ty];
            float4 b = *(const float4*)&Bs[kk][4 * tx];
            float av[4] = {a.x, a.y, a.z, a.w};
            float bv[4] = {b.x, b.y, b.z, b.w};
#pragma unroll
            for (int i = 0; i < 4; i++)
#pragma unroll
                for (int j = 0; j < 4; j++)
                    acc[i][j] = fmaf(av[i], bv[j], acc[i][j]);
        }
        __syncthreads();
    }

    float* pz = part + (long)blockIdx.z * M * N;
#pragma unroll
    for (int i = 0; i < 4; i++) {
        int gr = rowBase + 4 * ty + i;
        if (gr >= M) continue;
#pragma unroll
        for (int j = 0; j < 4; j++) {
            int gc = colBase + 4 * tx + j;
            if (gc >= N) continue;
            pz[(long)gr * N + gc] = acc[i][j];
        }
    }
}

__global__ void splitk_reduce(const float* __restrict__ part, const float* __restrict__ addsrc,
                              float* __restrict__ C, long MN, int sk) {
    long i = (long)blockIdx.x * blockDim.x + threadIdx.x;
    if (i >= MN) return;
    float s = 0.f;
    for (int z = 0; z < sk; z++) s += part[(long)z * MN + i];
    if (addsrc) s += addsrc[i];
    C[i] = s;
}

// ---------- row softmax over [R, n] ----------
__global__ void softmax_rows(float* __restrict__ S, int n) {
    int row = blockIdx.x;
    float* p = S + (long)row * n;
    __shared__ float red[256];
    int tid = threadIdx.x;
    float m = -1e30f;
    for (int j = tid; j < n; j += 256) m = fmaxf(m, p[j]);
    red[tid] = m; __syncthreads();
    for (int s = 128; s > 0; s >>= 1) { if (tid < s) red[tid] = fmaxf(red[tid], red[tid + s]); __syncthreads(); }
    m = red[0]; __syncthreads();
    float sum = 0.f;
    for (int j = tid; j < n; j += 256) { float e = expf(p[j] - m); p[j] = e; sum += e; }
    red[tid] = sum; __syncthreads();
    for (int s = 128; s > 0; s >>= 1) { if (tid < s) red[tid] += red[tid + s]; __syncthreads(); }
    float inv = 1.0f / red[0];
    for (int j = tid; j < n; j += 256) p[j] *= inv;
}

// ---------- scatter (last write wins, numpy semantics) ----------
__global__ void scatter_init(int* last, const int* __restrict__ com, int B) {
    int i = blockIdx.x * blockDim.x + threadIdx.x;
    if (i < B) last[com[i]] = -1;
}
__global__ void scatter_max(int* last, const int* __restrict__ com, int B) {
    int i = blockIdx.x * blockDim.x + threadIdx.x;
    if (i < B) atomicMax(&last[com[i]], i);
}
__global__ void scatter_write(const int* __restrict__ last, const int* __restrict__ com,
                              const float* __restrict__ fused, float* __restrict__ x, int B, int D) {
    int i = blockIdx.x;
    int node = com[i];
    if (last[node] != i) return;
    for (int c = threadIdx.x; c < D; c += blockDim.x)
        x[(long)node * D + c] = fused[(long)i * D + c];
}

// ---------- GAT per-node attention coefficients ----------
__global__ void node_attn_coef(const float* __restrict__ h, const float* __restrict__ a_src,
                               const float* __restrict__ a_dst, float* __restrict__ es,
                               float* __restrict__ ed, int N, int H, int C) {
    int idx = blockIdx.x * blockDim.x + threadIdx.x;
    if (idx >= N * H) return;
    int n = idx / H, hh = idx % H;
    const float* hp = h + (long)n * H * C + (long)hh * C;
    const float* as = a_src + hh * C;
    const float* ad = a_dst + hh * C;
    float s = 0.f, d = 0.f;
    for (int c = 0; c < C; c++) { float v = hp[c]; s += v * as[c]; d += v * ad[c]; }
    es[idx] = s; ed[idx] = d;
}

// ================== CSR build ==================
__global__ void deg_init(int* deg, int n) {
    int i = blockIdx.x * blockDim.x + threadIdx.x;
    if (i < n) deg[i] = 1;
}
__global__ void deg_count(const int* __restrict__ dst, int* deg, int E) {
    int e = blockIdx.x * blockDim.x + threadIdx.x;
    if (e < E) atomicAdd(&deg[dst[e]], 1);
}
#define SCAN_BLOCK 1024
__global__ __launch_bounds__(SCAN_BLOCK) void scan_rowptr(const int* __restrict__ deg, int* __restrict__ rowptr, int n) {
    __shared__ int tmp[SCAN_BLOCK];
    __shared__ int carry;
    int tid = threadIdx.x;
    if (tid == 0) carry = 0;
    __syncthreads();
    for (int base = 0; base < n; base += SCAN_BLOCK) {
        int i = base + tid;
        int v = (i < n) ? deg[i] : 0;
        tmp[tid] = v; __syncthreads();
        for (int off = 1; off < SCAN_BLOCK; off <<= 1) {
            int t2 = (tid >= off) ? tmp[tid - off] : 0;
            __syncthreads();
            tmp[tid] += t2;
            __syncthreads();
        }
        int incl = tmp[tid];
        if (i < n) rowptr[i + 1] = carry + incl;
        __syncthreads();
        if (tid == SCAN_BLOCK - 1) carry += incl;
        __syncthreads();
    }
    if (tid == 0) rowptr[0] = 0;
}
__global__ void copy_i32(const int* __restrict__ a, int* __restrict__ b, int n) {
    int i = blockIdx.x * blockDim.x + threadIdx.x;
    if (i < n) b[i] = a[i];
}
__global__ void csr_fill(const int* __restrict__ src, const int* __restrict__ dst,
                         int* cursor, int* __restrict__ csr_src, int E) {
    int e = blockIdx.x * blockDim.x + threadIdx.x;
    if (e >= E) return;
    int slot = atomicAdd(&cursor[dst[e]], 1);
    csr_src[slot] = src[e];
}
__global__ void csr_fill_loops(int* cursor, int* __restrict__ csr_src, int n) {
    int i = blockIdx.x * blockDim.x + threadIdx.x;
    if (i >= n) return;
    int slot = atomicAdd(&cursor[i], 1);
    csr_src[slot] = i;
}

// ---------- segment max + denom per (node, head), gather over CSR ----------
__global__ void csr_maxden(const int* __restrict__ rowptr, const int* __restrict__ csr_src,
                           const float* __restrict__ es, const float* __restrict__ ed,
                           float* __restrict__ m, float* __restrict__ den, int N, int H) {
    int idx = blockIdx.x * blockDim.x + threadIdx.x;
    if (idx >= N * H) return;
    int d = idx / H, h = idx - d * H;
    float edv = ed[idx];
    int b = rowptr[d], e = rowptr[d + 1];
    float mm = -1e30f;
    for (int s0 = b; s0 < e; s0++) {
        int s = csr_src[s0];
        mm = fmaxf(mm, leaky(es[s * H + h] + edv));
    }
    float dn = 0.f;
    for (int s0 = b; s0 < e; s0++) {
        int s = csr_src[s0];
        dn += expf(leaky(es[s * H + h] + edv) - mm);
    }
    m[idx] = mm;
    den[idx] = dn;
}

// ---------- layer-1 aggregate + bias + ELU + (row @ W2) fused ----------
__global__ __launch_bounds__(128) void csr_agg1_fused(
    const int* __restrict__ rowptr, const int* __restrict__ csr_src,
    const float* __restrict__ es, const float* __restrict__ ed,
    const float* __restrict__ m1, const float* __restrict__ den1,
    const float* __restrict__ h1, const float* __restrict__ b1,
    const float* __restrict__ W2, float* __restrict__ h2, int N)
{
    int d = blockIdx.x;
    int t = threadIdx.x;
    __shared__ float row[HC1];
    __shared__ float part[128][OUTC + 1];

    int b = rowptr[d], e = rowptr[d + 1];
    float ed0 = ed[d * 3 + 0], ed1 = ed[d * 3 + 1], ed2 = ed[d * 3 + 2];
    float mm0 = m1[d * 3 + 0], mm1 = m1[d * 3 + 1], mm2 = m1[d * 3 + 2];
    float i0 = 1.f / (den1[d * 3 + 0] + 1e-16f);
    float i1 = 1.f / (den1[d * 3 + 1] + 1e-16f);
    float i2 = 1.f / (den1[d * 3 + 2] + 1e-16f);

    float a0 = 0.f, a1 = 0.f, a2 = 0.f;
    for (int s0 = b; s0 < e; s0++) {
        int s = csr_src[s0];
        float e0 = es[s * 3 + 0], e1 = es[s * 3 + 1], e2 = es[s * 3 + 2];
        float al0 = expf(leaky(e0 + ed0) - mm0) * i0;
        float al1 = expf(leaky(e1 + ed1) - mm1) * i1;
        float al2 = expf(leaky(e2 + ed2) - mm2) * i2;
        const float* hp = h1 + (long)s * HC1;
        a0 = fmaf(hp[t],       al0, a0);
        a1 = fmaf(hp[t + 128], al1, a1);
        a2 = fmaf(hp[t + 256], al2, a2);
    }
    float v;
    v = a0 + b1[t];       row[t]       = v > 0.f ? v : expf(v) - 1.f;
    v = a1 + b1[t + 128]; row[t + 128] = v > 0.f ? v : expf(v) - 1.f;
    v = a2 + b1[t + 256]; row[t + 256] = v > 0.f ? v : expf(v) - 1.f;
    __syncthreads();

    float pc[OUTC];
#pragma unroll
    for (int c = 0; c < OUTC; c++) pc[c] = 0.f;
    for (int k = t; k < HC1; k += 128) {
        float rv = row[k];
        const float* w = W2 + (long)k * OUTC;
#pragma unroll
        for (int c = 0; c < OUTC; c++) pc[c] = fmaf(rv, w[c], pc[c]);
    }
#pragma unroll
    for (int c = 0; c < OUTC; c++) part[t][c] = pc[c];
    __syncthreads();
    for (int off = 64; off > 0; off >>= 1) {
        if (t < off) {
#pragma unroll
            for (int c = 0; c < OUTC; c++) part[t][c] += part[t + off][c];
        }
        __syncthreads();
    }
    if (t < OUTC) h2[(long)d * OUTC + t] = part[0][t];
}

// ---------- layer-2 aggregate + bias ----------
__global__ void csr_agg2(const int* __restrict__ rowptr, const int* __restrict__ csr_src,
                         const float* __restrict__ es, const float* __restrict__ ed,
                         const float* __restrict__ m2, const float* __restrict__ den2,
                         const float* __restrict__ h2, const float* __restrict__ b2,
                         float* __restrict__ emb, int N)
{
    int idx = blockIdx.x * blockDim.x + threadIdx.x;
    if (idx >= N * OUTC) return;
    int d = idx / OUTC, c = idx - d * OUTC;
    float edv = ed[d], mm = m2[d], inv = 1.f / (den2[d] + 1e-16f);
    int b = rowptr[d], e = rowptr[d + 1];
    float acc = 0.f;
    for (int s0 = b; s0 < e; s0++) {
        int s = csr_src[s0];
        float al = expf(leaky(es[s] + edv) - mm) * inv;
        acc = fmaf(h2[(long)s * OUTC + c], al, acc);
    }
    emb[idx] = acc + b2[c];
}

// ---------- pair scores ----------
__global__ void pair_score(const int* __restrict__ pairs, const float* __restrict__ emb,
                           float* __restrict__ out, int P) {
    int p = blockIdx.x * blockDim.x + threadIdx.x;
    if (p >= P) return;
    int i0 = pairs[2 * p], i1 = pairs[2 * p + 1];
    const float* a = emb + (long)i0 * OUTC;
    const float* b = emb + (long)i1 * OUTC;
    float s = 0.f;
#pragma unroll
    for (int c = 0; c < OUTC; c++) s += a[c] * b[c];
    out[p] = s;
}

extern "C" void kernel_launch(void* const* d_in, const int* in_sizes, int n_in,
                              void* d_out, int out_size, void* d_ws, size_t ws_size,
                              hipStream_t stream) {
    const float* fsub = (const float*)d_in[0];
    const float* fcom = (const float*)d_in[1];
    float*       x    = (float*)d_in[2];
    const int*   com  = (const int*)d_in[3];
    const int*   ei   = (const int*)d_in[4];
    const int*   pidx = (const int*)d_in[5];
    const float* Wq = (const float*)d_in[6];  const float* bq = (const float*)d_in[7];
    const float* Wk = (const float*)d_in[8];  const float* bk = (const float*)d_in[9];
    const float* Wv = (const float*)d_in[10]; const float* bv = (const float*)d_in[11];
    const float* Wf = (const float*)d_in[12]; const float* bf = (const float*)d_in[13];
    const float* W1 = (const float*)d_in[14];
    const float* as1 = (const float*)d_in[15]; const float* ad1 = (const float*)d_in[16];
    const float* b1 = (const float*)d_in[17];
    const float* W2 = (const float*)d_in[18];
    const float* as2 = (const float*)d_in[19]; const float* ad2 = (const float*)d_in[20];
    const float* b2 = (const float*)d_in[21];
    float* out = (float*)d_out;

    const int* src = ei;
    const int* dst = ei + NE;

    char* ws = (char*)d_ws;
    // ---- phase 1 (attention): 0 .. 91.7 MB ----
    float* S    = (float*)(ws + 0);          // 67,108,864
    float* q    = (float*)(ws + 67108864);
    float* kbuf = (float*)(ws + 72024064);
    float* vbuf = (float*)(ws + 76939264);
    float* attn = (float*)(ws + 81854464);
    float* fus  = (float*)(ws + 86769664);   // ends 91,684,864
    // ---- phase 2 (GAT) ----
    float*    h1   = (float*)(ws + 0);          // 76,800,000 (after attention done)
    float*    es1  = (float*)(ws + 92000000);
    float*    ed1  = (float*)(ws + 92600000);
    float*    m1   = (float*)(ws + 93200000);
    float*    den1 = (float*)(ws + 93800000);
    float*    es2  = (float*)(ws + 94400000);
    float*    ed2  = (float*)(ws + 94600000);
    float*    m2   = (float*)(ws + 94800000);
    float*    den2 = (float*)(ws + 95000000);
    float*    h2   = (float*)(ws + 95200000);
    float*    embp = (float*)(ws + 97200000);
    int*      last = (int*)(ws + 99200000);
    int*      deg  = (int*)(ws + 99400000);
    int*      curs = (int*)(ws + 99600000);
    int*      rowp = (int*)(ws + 99800000);
    int*      csrc = (int*)(ws + 100000016);    // ends ~102.2 MB
    // split-K partials (live only during attention phase; overlaps CSR zone harmlessly)
    float*    part = (float*)(ws + 102400000);  // 8*4096*300*4 = 39,321,600 -> ends ~141.7 MB

    const float inv_sqrt_d = 1.0f / sqrtf((float)FEAT);

    // ===== 1. cross attention =====
    hipLaunchKernelGGL((gemm_rt<false>), dim3(cdiv(FEAT,BN), cdiv(BP,BM)), dim3(256), 0, stream,
                       fsub, Wq, bq, nullptr, q, BP, FEAT, FEAT, 1.0f);
    hipLaunchKernelGGL((gemm_rt<false>), dim3(cdiv(FEAT,BN), cdiv(BP,BM)), dim3(256), 0, stream,
                       fcom, Wk, bk, nullptr, kbuf, BP, FEAT, FEAT, 1.0f);
    hipLaunchKernelGGL((gemm_rt<false>), dim3(cdiv(FEAT,BN), cdiv(BP,BM)), dim3(256), 0, stream,
                       fcom, Wv, bv, nullptr, vbuf, BP, FEAT, FEAT, 1.0f);
    hipLaunchKernelGGL((gemm_rt<true>), dim3(cdiv(BP,BN), cdiv(BP,BM)), dim3(256), 0, stream,
                       q, kbuf, nullptr, nullptr, S, BP, BP, FEAT, inv_sqrt_d);
    hipLaunchKernelGGL(softmax_rows, dim3(BP), dim3(256), 0, stream, S, BP);
    // attn = fsub + S @ v   (split-K over K=4096, sk=8)
    {
        const int SK = 8, KC = BP / SK;
        hipLaunchKernelGGL(gemm_splitk, dim3(cdiv(FEAT,BN), cdiv(BP,BM), SK), dim3(256), 0, stream,
                           S, vbuf, part, BP, FEAT, BP, KC);
        long MN = (long)BP * FEAT;
        hipLaunchKernelGGL(splitk_reduce, dim3(cdiv((int)MN,256)), dim3(256), 0, stream,
                           part, fsub, attn, MN, SK);
    }
    hipLaunchKernelGGL((gemm_rt<false>), dim3(cdiv(FEAT,BN), cdiv(BP,BM)), dim3(256), 0, stream,
                       attn, Wf, bf, nullptr, fus, BP, FEAT, FEAT, 1.0f);

    // ===== 2. scatter fused into x (last write wins) =====
    hipLaunchKernelGGL(scatter_init, dim3(cdiv(BP,256)), dim3(256), 0, stream, last, com, BP);
    hipLaunchKernelGGL(scatter_max,  dim3(cdiv(BP,256)), dim3(256), 0, stream, last, com, BP);
    hipLaunchKernelGGL(scatter_write, dim3(BP), dim3(128), 0, stream, last, com, fus, x, BP, FEAT);

    // ===== 3. CSR build =====
    hipLaunchKernelGGL(deg_init,  dim3(cdiv(NN,256)), dim3(256), 0, stream, deg, NN);
    hipLaunchKernelGGL(deg_count, dim3(cdiv(NE,256)), dim3(256), 0, stream, dst, deg, NE);
    hipLaunchKernelGGL(scan_rowptr, dim3(1), dim3(SCAN_BLOCK), 0, stream, deg, rowp, NN);
    hipLaunchKernelGGL(copy_i32, dim3(cdiv(NN,256)), dim3(256), 0, stream, rowp, curs, NN);
    hipLaunchKernelGGL(csr_fill, dim3(cdiv(NE,256)), dim3(256), 0, stream, src, dst, curs, csrc, NE);
    hipLaunchKernelGGL(csr_fill_loops, dim3(cdiv(NN,256)), dim3(256), 0, stream, curs, csrc, NN);

    // ===== 4. GAT layer 1 =====
    hipLaunchKernelGGL((gemm_rt<false>), dim3(cdiv(HC1,BN), cdiv(NN,BM)), dim3(256), 0, stream,
                       x, W1, nullptr, nullptr, h1, NN, HC1, FEAT, 1.0f);
    hipLaunchKernelGGL(node_attn_coef, dim3(cdiv(NN*HEADS,256)), dim3(256), 0, stream,
                       h1, as1, ad1, es1, ed1, NN, HEADS, HID);
    hipLaunchKernelGGL(csr_maxden, dim3(cdiv(NN*HEADS,256)), dim3(256), 0, stream,
                       rowp, csrc, es1, ed1, m1, den1, NN, HEADS);
    hipLaunchKernelGGL(csr_agg1_fused, dim3(NN), dim3(128), 0, stream,
                       rowp, csrc, es1, ed1, m1, den1, h1, b1, W2, h2, NN);

    // ===== 5. GAT layer 2 =====
    hipLaunchKernelGGL(node_attn_coef, dim3(cdiv(NN,256)), dim3(256), 0, stream,
                       h2, as2, ad2, es2, ed2, NN, 1, OUTC);
    hipLaunchKernelGGL(csr_maxden, dim3(cdiv(NN,256)), dim3(256), 0, stream,
                       rowp, csrc, es2, ed2, m2, den2, NN, 1);
    hipLaunchKernelGGL(csr_agg2, dim3(cdiv(NN*OUTC,256)), dim3(256), 0, stream,
                       rowp, csrc, es2, ed2, m2, den2, h2, b2, embp, NN);

    // ===== 6. pair scores =====
    hipLaunchKernelGGL(pair_score, dim3(cdiv(NP,256)), dim3(256), 0, stream, pidx, embp, out, NP);
}